// Round 5
// baseline (625.362 us; speedup 1.0000x reference)
//
#include <hip/hip_runtime.h>
#include <hip/hip_bf16.h>

#define N_NODES 50000
#define N_EDGES 800000
#define IN_F 512
#define HID 256
#define HEADS 8
#define DHEAD 32
#define N_CLS 40
#define NCLS_PAD 64

typedef __bf16 bf16x8 __attribute__((ext_vector_type(8)));
typedef float f32x4 __attribute__((ext_vector_type(4)));
typedef float f32x2 __attribute__((ext_vector_type(2)));

// f32 att/bias workspace layout (in floats)
#define AT_AL0 0
#define AT_AR0 256
#define AT_AL1 512
#define AT_AR1 768
#define AT_AL2 1024
#define AT_AR2 1088
#define AT_B0  1152
#define AT_B1  1408
#define AT_B2  1664
#define AT_SZ  1792

__device__ __forceinline__ float ldflag(const void* p, long long i, int isbf) {
  return isbf ? __bfloat162float(((const __hip_bfloat16*)p)[i])
              : ((const float*)p)[i];
}
// unpack a packed bf16 pair (u32): low-address element in low 16 bits
__device__ __forceinline__ float blo(unsigned u) { return __uint_as_float(u << 16); }
__device__ __forceinline__ float bhi(unsigned u) { return __uint_as_float(u & 0xffff0000u); }
// bf16 pair -> f32x2 (feeds v_pk_fma_f32)
__device__ __forceinline__ f32x2 bpair(unsigned u) {
  f32x2 r;
  r.x = __uint_as_float(u << 16);
  r.y = __uint_as_float(u & 0xffff0000u);
  return r;
}
// pack two floats -> bf16 pair in u32
__device__ __forceinline__ unsigned pk2(float a, float b) {
  unsigned x = __bfloat16_as_ushort(__float2bfloat16(a));
  unsigned y = __bfloat16_as_ushort(__float2bfloat16(b));
  return x | (y << 16);
}
// 8 A-elements (bf16 packed in uint4) from base element-offset; f32 input cast-fused
__device__ __forceinline__ uint4 ldA8(const void* A, int isbf, size_t base) {
  if (isbf) return *(const uint4*)((const unsigned short*)A + base);
  const float* ap = (const float*)A + base;
  float4 f1 = *(const float4*)ap;
  float4 f2 = *(const float4*)(ap + 4);
  return make_uint4(pk2(f1.x, f1.y), pk2(f1.z, f1.w), pk2(f2.x, f2.y), pk2(f2.z, f2.w));
}
__device__ __forceinline__ bf16x8 as_bf(uint4 v) {
  union { uint4 u; bf16x8 b; } x; x.u = v; return x.b;
}

// ---------------- dtype detect + constant prep + cursor zero (1 block) ----------------
__global__ void k_detect_prep(const unsigned short* __restrict__ raw, int* __restrict__ flag,
                              const void* al0, const void* ar0, const void* al1, const void* ar1,
                              const void* al2, const void* ar2, const void* b0, const void* b1,
                              const void* b2, float* __restrict__ att, int* __restrict__ cursor) {
  __shared__ int cnt[256];
  int t = threadIdx.x;
  for (int i = t; i < N_NODES; i += 256) cursor[i] = 0;   // replaces memset #1
  int c = 0;
  for (int i = t; i < 8192; i += 256) {
    int e = (raw[i] >> 7) & 0xFF;
    if (e >= 0x90) c++;
  }
  cnt[t] = c;
  __syncthreads();
  for (int s = 128; s; s >>= 1) {
    if (t < s) cnt[t] += cnt[t + s];
    __syncthreads();
  }
  __shared__ int sflag;
  if (t == 0) { sflag = (cnt[0] > 64) ? 0 : 1; *flag = sflag; }
  __syncthreads();
  int isbf = sflag;
  att[AT_AL0 + t] = ldflag(al0, t, isbf);
  att[AT_AR0 + t] = ldflag(ar0, t, isbf);
  att[AT_AL1 + t] = ldflag(al1, t, isbf);
  att[AT_AR1 + t] = ldflag(ar1, t, isbf);
  att[AT_B0 + t]  = ldflag(b0, t, isbf);
  att[AT_B1 + t]  = ldflag(b1, t, isbf);
  if (t < N_CLS) {
    att[AT_AL2 + t] = ldflag(al2, t, isbf);
    att[AT_AR2 + t] = ldflag(ar2, t, isbf);
    att[AT_B2 + t]  = ldflag(b2, t, isbf);
  }
}

// ---------------- CSR build (by dst) ----------------
__global__ void k_hist(const int* __restrict__ dst, int* __restrict__ cnt) {
  int e = blockIdx.x * blockDim.x + threadIdx.x;
  if (e < N_EDGES) atomicAdd(&cnt[dst[e]], 1);
}

#define SCAN_B 512
#define SCAN_NB ((N_NODES + SCAN_B - 1) / SCAN_B)   // 98

__global__ __launch_bounds__(SCAN_B) void k_scan_blocks(const int* __restrict__ deg,
                                                        int* __restrict__ excl,
                                                        int* __restrict__ partial) {
  __shared__ int buf[SCAN_B];
  int t = threadIdx.x;
  int i = blockIdx.x * SCAN_B + t;
  int v = (i < N_NODES) ? deg[i] : 0;
  buf[t] = v;
  __syncthreads();
  for (int off = 1; off < SCAN_B; off <<= 1) {
    int x = (t >= off) ? buf[t - off] : 0;
    __syncthreads();
    buf[t] += x;
    __syncthreads();
  }
  if (i < N_NODES) excl[i] = buf[t] - v;
  if (t == SCAN_B - 1) partial[blockIdx.x] = buf[t];
}

__global__ void k_scan_partials(int* __restrict__ partial, int* __restrict__ rowptr) {
  __shared__ int buf[SCAN_NB];
  int t = threadIdx.x;
  if (t < SCAN_NB) buf[t] = partial[t];
  __syncthreads();
  if (t == 0) {
    int run = 0;
    for (int b = 0; b < SCAN_NB; b++) { int v = buf[b]; buf[b] = run; run += v; }
    rowptr[N_NODES] = run;
  }
  __syncthreads();
  if (t < SCAN_NB) partial[t] = buf[t];
}

// adds partial sums AND re-zeros cursor for k_scatter (replaces memset #2)
__global__ void k_scan_add(int* __restrict__ rowptr, const int* __restrict__ partial,
                           int* __restrict__ cursor) {
  int i = blockIdx.x * blockDim.x + threadIdx.x;
  if (i < N_NODES) {
    rowptr[i] += partial[i / SCAN_B];
    cursor[i] = 0;
  }
}

__global__ void k_scatter(const int* __restrict__ src, const int* __restrict__ dst,
                          const int* __restrict__ rowptr, int* __restrict__ cursor,
                          int* __restrict__ csr_src) {
  int e = blockIdx.x * blockDim.x + threadIdx.x;
  if (e < N_EDGES) {
    int d = dst[e];
    int pos = rowptr[d] + atomicAdd(&cursor[d], 1);
    csr_src[pos] = src[e];
  }
}

// ---------------- all 3 weight transposes in one kernel -> bf16 [Ndst][K] ----------------
#define TW0 (HID * IN_F)            // 131072
#define TW1 (TW0 + HID * HID)       // 196608
#define TW2 (TW1 + NCLS_PAD * HID)  // 212992
__global__ void k_transpose_all(const void* __restrict__ W0, const void* __restrict__ W1,
                                const void* __restrict__ W2,
                                __hip_bfloat16* __restrict__ w0t, __hip_bfloat16* __restrict__ w1t,
                                __hip_bfloat16* __restrict__ w2t, const int* __restrict__ flag) {
  int isbf = *flag;
  int i = blockIdx.x * blockDim.x + threadIdx.x;
  if (i < TW0) {                       // w0t[256][512] <- W0[512][256]
    int n = i >> 9, k = i & 511;
    w0t[i] = __float2bfloat16(ldflag(W0, (long long)k * HID + n, isbf));
  } else if (i < TW1) {                // w1t[256][256] <- W1[256][256]
    int j = i - TW0;
    int n = j >> 8, k = j & 255;
    w1t[j] = __float2bfloat16(ldflag(W1, (long long)k * HID + n, isbf));
  } else if (i < TW2) {                // w2t[64][256] <- W2[256][40], pad cols 40..63
    int j = i - TW1;
    int n = j >> 8, k = j & 255;
    float v = (n < N_CLS) ? ldflag(W2, (long long)k * N_CLS + n, isbf) : 0.f;
    w2t[j] = __float2bfloat16(v);
  }
}

// ---------------- MFMA bf16 GEMM: wave-autonomous 64x64 tiles, NO LDS, NO barriers ----------------
// Rounds 1-4 post-mortem: four different LDS/barrier schedules all ~80 µs (MfmaUtil ~6%) --
// the block-wide barrier every K-step makes memory queues burst-and-drain (A-stream 0.65 TB/s),
// while the barrier-free k_aggregate8 sustains 3.36 TB/s on RANDOM gathers. Fix: drop LDS
// entirely. The MFMA fragment layout (A: lane -> A[row0+16i+lm][k0+quad*8..+8]) is directly
// loadable with one global_load_dwordx4 per fragment, and Bt[col][k] has the identical pattern
// (byte-identical addresses to what the verified k_gemm128 ds_reads delivered). Each wave owns
// a 64x64 output tile: per K-step 8 frag loads (reg-prefetched 1 step ahead) + 16 MFMAs, never
// synchronizes -> continuous issue, latency hidden by TLP (3128 independent waves).
// Block = 4 waves = the 4 nb-tiles of one mb (when N=256) -> same 64 A-rows, L1/L2 shared.
// f32-A (layer 0 fallback): per-fragment cast-fuse in ldA8 (uniform branch).
// fuse_eler: wave's 64 cols = exactly 2 heads -> el/er in-epilogue.
__global__ __launch_bounds__(256) void k_gemmw(const void* __restrict__ A,
                                               const __hip_bfloat16* __restrict__ Bt,
                                               __hip_bfloat16* __restrict__ C,
                                               int M, int K, int N,
                                               const int* __restrict__ flag, int force_bf,
                                               const float* __restrict__ al,
                                               const float* __restrict__ ar,
                                               float* __restrict__ el,
                                               float* __restrict__ er, int fuse_eler) {
  const int isbf = force_bf ? 1 : *flag;
  int nblk = N >> 6;
  int wave = threadIdx.x >> 6, lane = threadIdx.x & 63;
  int tile = blockIdx.x * 4 + wave;
  int mb = tile / nblk;
  int nb = tile - mb * nblk;
  int m0 = mb * 64, n0 = nb * 64;
  if (m0 >= M) return;                 // wave-uniform; no barriers anywhere -> safe
  int lm = lane & 15, quad = lane >> 4;
  int koff = quad << 3;                // k-octet offset of this lane
  // per-fragment base offsets (element units); clamp tail rows (dup row M-1, store-guarded)
  size_t ab[4];
  const unsigned short* bb[4];
  #pragma unroll
  for (int i = 0; i < 4; i++) {
    int ga = m0 + i * 16 + lm;
    if (ga > M - 1) ga = M - 1;
    ab[i] = (size_t)ga * K + koff;
    bb[i] = (const unsigned short*)Bt + (size_t)(n0 + i * 16 + lm) * K + koff;
  }
  f32x4 acc[4][4] = {};
  uint4 a0[4], b0[4];
  #pragma unroll
  for (int i = 0; i < 4; i++) { a0[i] = ldA8(A, isbf, ab[i]); b0[i] = *(const uint4*)bb[i]; }
  int nk = K >> 5;
  for (int t = 1; t < nk; ++t) {
    int k0 = t << 5;
    uint4 a1[4], b1[4];                // prefetch next K-step (compiler schedules past MFMAs)
    #pragma unroll
    for (int i = 0; i < 4; i++) {
      a1[i] = ldA8(A, isbf, ab[i] + k0);
      b1[i] = *(const uint4*)(bb[i] + k0);
    }
    #pragma unroll
    for (int mi = 0; mi < 4; mi++)
      #pragma unroll
      for (int ni = 0; ni < 4; ni++)
        acc[mi][ni] = __builtin_amdgcn_mfma_f32_16x16x32_bf16(as_bf(a0[mi]), as_bf(b0[ni]),
                                                              acc[mi][ni], 0, 0, 0);
    #pragma unroll
    for (int i = 0; i < 4; i++) { a0[i] = a1[i]; b0[i] = b1[i]; }
  }
  #pragma unroll
  for (int mi = 0; mi < 4; mi++)
    #pragma unroll
    for (int ni = 0; ni < 4; ni++)
      acc[mi][ni] = __builtin_amdgcn_mfma_f32_16x16x32_bf16(as_bf(a0[mi]), as_bf(b0[ni]),
                                                            acc[mi][ni], 0, 0, 0);
  // C/D layout: col = lane&15, row = quad*4 + r (m89/m91 verified)
  #pragma unroll
  for (int mi = 0; mi < 4; mi++) {
    #pragma unroll
    for (int r2 = 0; r2 < 4; r2++) {
      int gm = m0 + mi * 16 + (quad << 2) + r2;
      if (gm < M) {
        #pragma unroll
        for (int ni = 0; ni < 4; ni++) {
          int gn = n0 + ni * 16 + lm;
          C[(size_t)gm * N + gn] = __float2bfloat16(acc[mi][ni][r2]);
        }
      }
    }
  }
  if (fuse_eler) {
    // this wave's cols n0 .. n0+63 = heads h0, h0+1
    int h0 = n0 >> 5;
    float ala[4], ara[4];
    #pragma unroll
    for (int ni = 0; ni < 4; ni++) {
      int idx = (h0 + (ni >> 1)) * DHEAD + ((ni & 1) << 4) + lm;
      ala[ni] = al[idx];
      ara[ni] = ar[idx];
    }
    #pragma unroll
    for (int mi = 0; mi < 4; mi++)
      #pragma unroll
      for (int r2 = 0; r2 < 4; r2++) {
        int gm = m0 + mi * 16 + (quad << 2) + r2;
        #pragma unroll
        for (int hp = 0; hp < 2; hp++) {
          float pl = acc[mi][2 * hp][r2] * ala[2 * hp] + acc[mi][2 * hp + 1][r2] * ala[2 * hp + 1];
          float pr = acc[mi][2 * hp][r2] * ara[2 * hp] + acc[mi][2 * hp + 1][r2] * ara[2 * hp + 1];
          #pragma unroll
          for (int d = 1; d < 16; d <<= 1) {   // butterfly over the 16 lm lanes (same quad)
            pl += __shfl_xor(pl, d, 16);
            pr += __shfl_xor(pr, d, 16);
          }
          if (lm == 0 && gm < M) {
            el[gm * HEADS + h0 + hp] = pl;
            er[gm * HEADS + h0 + hp] = pr;
          }
        }
      }
  }
}

// ---------------- el/er for layer 2 (1 head, 40 dims, stride 64) ----------------
__global__ void k_eler2(const __hip_bfloat16* __restrict__ feat2,
                        const float* __restrict__ al, const float* __restrict__ ar,
                        float* __restrict__ el, float* __restrict__ er) {
  int n = blockIdx.x * blockDim.x + threadIdx.x;
  if (n >= N_NODES) return;
  const __hip_bfloat16* f = feat2 + (size_t)n * NCLS_PAD;
  float sl = 0.f, sr = 0.f;
  for (int d = 0; d < N_CLS; d++) {
    float v = __bfloat162float(f[d]);
    sl += v * al[d];
    sr += v * ar[d];
  }
  el[n] = sl;
  er[n] = sr;
}

// ---------------- fused edge-softmax + aggregation, 8 slots x 32 lanes ----------------
// lane owns 8 channels (uint4/edge). No max-subtraction (shift-invariant, exp clamped).
// Unroll-2: two independent csr->el/feat gather chains in flight.
// f32x2 accumulators -> v_pk_fma_f32; 32-bit byte offsets -> saddr+voffset loads.
__global__ __launch_bounds__(256) void k_aggregate8(const int* __restrict__ rowptr,
                                                    const int* __restrict__ csr_src,
                                                    const uint4* __restrict__ feat_rows,
                                                    const float* __restrict__ el,
                                                    const float* __restrict__ er,
                                                    const float* __restrict__ bias,
                                                    __hip_bfloat16* __restrict__ out) {
  __shared__ float lds_acc[8][256];
  __shared__ float lds_l[8][32];
  int n = blockIdx.x;
  int t = threadIdx.x;
  int slot = t >> 5;      // 0..7
  int c = t & 31;         // channel group: channels c*8..c*8+7
  int hh = c >> 2;        // head of this group
  float er_n = er[n * HEADS + hh];
  int beg = rowptr[n], end = rowptr[n + 1];
  float l = 0.f;
  f32x2 a0 = {0.f, 0.f}, a1 = {0.f, 0.f}, a2 = {0.f, 0.f}, a3 = {0.f, 0.f};
  const char* fb = (const char*)feat_rows;
  unsigned cb = (unsigned)c << 4;
  int i = beg + slot;
  for (; i + 8 < end; i += 16) {
    int s1 = csr_src[i];
    int s2 = csr_src[i + 8];
    float el1 = el[s1 * HEADS + hh];
    float el2 = el[s2 * HEADS + hh];
    uint4 f1 = *(const uint4*)(fb + (((unsigned)s1 << 9) | cb));
    uint4 f2 = *(const uint4*)(fb + (((unsigned)s2 << 9) | cb));
    float x1 = el1 + er_n, x2 = el2 + er_n;
    float e1 = x1 > 0.f ? x1 : 0.2f * x1;
    float e2 = x2 > 0.f ? x2 : 0.2f * x2;
    float p1 = __expf(fminf(e1, 60.f));
    float p2 = __expf(fminf(e2, 60.f));
    l += p1 + p2;
    a0 += bpair(f1.x) * p1; a1 += bpair(f1.y) * p1;
    a2 += bpair(f1.z) * p1; a3 += bpair(f1.w) * p1;
    a0 += bpair(f2.x) * p2; a1 += bpair(f2.y) * p2;
    a2 += bpair(f2.z) * p2; a3 += bpair(f2.w) * p2;
  }
  if (i < end) {
    int s = csr_src[i];
    float elv = el[s * HEADS + hh];
    uint4 fv = *(const uint4*)(fb + (((unsigned)s << 9) | cb));
    float x = elv + er_n;
    float e = x > 0.f ? x : 0.2f * x;
    float p = __expf(fminf(e, 60.f));
    l += p;
    a0 += bpair(fv.x) * p; a1 += bpair(fv.y) * p;
    a2 += bpair(fv.z) * p; a3 += bpair(fv.w) * p;
  }
  *(float4*)&lds_acc[slot][c * 8]     = make_float4(a0.x, a0.y, a1.x, a1.y);
  *(float4*)&lds_acc[slot][c * 8 + 4] = make_float4(a2.x, a2.y, a3.x, a3.y);
  lds_l[slot][c] = l;
  __syncthreads();
  float a = 0.f, L = 0.f;
  #pragma unroll
  for (int s2 = 0; s2 < 8; s2++) { a += lds_acc[s2][t]; L += lds_l[s2][t >> 3]; }
  float o = a / fmaxf(L, 1e-9f) + bias[t];
  o = fmaxf(o, 0.f);                            // ReLU (layers 0,1)
  out[(size_t)n * HID + t] = __float2bfloat16(o);
}

// ---------------- layer 2 aggregate: 32 slots x 8 lanes (64-ch padded rows) ----------------
__global__ __launch_bounds__(256) void k_aggregate1(const int* __restrict__ rowptr,
                                                    const int* __restrict__ csr_src,
                                                    const uint4* __restrict__ fr2,  // [N][8] uint4
                                                    const float* __restrict__ el,
                                                    const float* __restrict__ er,
                                                    const float* __restrict__ bias,
                                                    void* __restrict__ out,
                                                    const int* __restrict__ flag) {
  __shared__ float lds_acc[32][64];
  __shared__ float lds_l[32][8];
  int isbf = *flag;
  int n = blockIdx.x;
  int t = threadIdx.x;
  int slot = t >> 3;      // 0..31
  int c = t & 7;
  float er_n = er[n];
  int beg = rowptr[n], end = rowptr[n + 1];
  float l = 0.f;
  f32x2 a0 = {0.f, 0.f}, a1 = {0.f, 0.f}, a2 = {0.f, 0.f}, a3 = {0.f, 0.f};
  const char* fb = (const char*)fr2;
  unsigned cb = (unsigned)c << 4;
  int i = beg + slot;
  for (; i + 32 < end; i += 64) {
    int s1 = csr_src[i], s2 = csr_src[i + 32];
    float el1 = el[s1], el2 = el[s2];
    uint4 f1 = *(const uint4*)(fb + (((unsigned)s1 << 7) | cb));
    uint4 f2 = *(const uint4*)(fb + (((unsigned)s2 << 7) | cb));
    float x1 = el1 + er_n, x2 = el2 + er_n;
    float e1 = x1 > 0.f ? x1 : 0.2f * x1;
    float e2 = x2 > 0.f ? x2 : 0.2f * x2;
    float p1 = __expf(fminf(e1, 60.f));
    float p2 = __expf(fminf(e2, 60.f));
    l += p1 + p2;
    a0 += bpair(f1.x) * p1; a1 += bpair(f1.y) * p1;
    a2 += bpair(f1.z) * p1; a3 += bpair(f1.w) * p1;
    a0 += bpair(f2.x) * p2; a1 += bpair(f2.y) * p2;
    a2 += bpair(f2.z) * p2; a3 += bpair(f2.w) * p2;
  }
  if (i < end) {
    int s = csr_src[i];
    float x = el[s] + er_n;
    uint4 fv = *(const uint4*)(fb + (((unsigned)s << 7) | cb));
    float e = x > 0.f ? x : 0.2f * x;
    float p = __expf(fminf(e, 60.f));
    l += p;
    a0 += bpair(fv.x) * p; a1 += bpair(fv.y) * p;
    a2 += bpair(fv.z) * p; a3 += bpair(fv.w) * p;
  }
  *(float4*)&lds_acc[slot][c * 8]     = make_float4(a0.x, a0.y, a1.x, a1.y);
  *(float4*)&lds_acc[slot][c * 8 + 4] = make_float4(a2.x, a2.y, a3.x, a3.y);
  lds_l[slot][c] = l;
  __syncthreads();
  if (t < N_CLS) {
    float a = 0.f, L = 0.f;
    #pragma unroll
    for (int s2 = 0; s2 < 32; s2++) { a += lds_acc[s2][t]; L += lds_l[s2][t >> 3]; }
    float o = a / fmaxf(L, 1e-9f) + bias[t];    // no ReLU on output layer
    if (isbf) ((__hip_bfloat16*)out)[(size_t)n * N_CLS + t] = __float2bfloat16(o);
    else      ((float*)out)[(size_t)n * N_CLS + t] = o;
  }
}

// ---------------- launch ----------------
static inline size_t align_up(size_t x) { return (x + 255) & ~(size_t)255; }

extern "C" void kernel_launch(void* const* d_in, const int* in_sizes, int n_in,
                              void* d_out, int out_size, void* d_ws, size_t ws_size,
                              hipStream_t stream) {
  const void* in_feat = d_in[0];
  const int* src = (const int*)d_in[1];
  const int* dst = (const int*)d_in[2];
  const void* W0  = d_in[3];
  const void* al0 = d_in[4];
  const void* ar0 = d_in[5];
  const void* b0  = d_in[6];
  const void* W1  = d_in[7];
  const void* al1 = d_in[8];
  const void* ar1 = d_in[9];
  const void* b1  = d_in[10];
  const void* W2  = d_in[11];
  const void* al2 = d_in[12];
  const void* ar2 = d_in[13];
  const void* b2  = d_in[14];

  char* p = (char*)d_ws;
  int* flag = (int*)p;                   p += 256;
  float* att = (float*)p;                p += align_up(AT_SZ * sizeof(float));
  int* rowptr = (int*)p;                 p += align_up((N_NODES + 1) * sizeof(int));
  int* cursor = (int*)p;                 p += align_up(N_NODES * sizeof(int));
  int* csr_src = (int*)p;                p += align_up(N_EDGES * sizeof(int));
  int* partial = (int*)p;                p += align_up(SCAN_NB * sizeof(int));
  __hip_bfloat16* feat16 = (__hip_bfloat16*)p; p += align_up((size_t)N_NODES * HID * sizeof(__hip_bfloat16));
  __hip_bfloat16* h16 = (__hip_bfloat16*)p;    p += align_up((size_t)N_NODES * HID * sizeof(__hip_bfloat16));
  float* el = (float*)p;                 p += align_up((size_t)N_NODES * HEADS * sizeof(float));
  float* er = (float*)p;                 p += align_up((size_t)N_NODES * HEADS * sizeof(float));
  __hip_bfloat16* w0t = (__hip_bfloat16*)p;    p += align_up((size_t)HID * IN_F * sizeof(__hip_bfloat16));
  __hip_bfloat16* w1t = (__hip_bfloat16*)p;    p += align_up((size_t)HID * HID * sizeof(__hip_bfloat16));
  __hip_bfloat16* w2t = (__hip_bfloat16*)p;    p += align_up((size_t)NCLS_PAD * HID * sizeof(__hip_bfloat16));

  const int EB = (N_EDGES + 255) / 256;
  const int MB64 = (N_NODES + 63) / 64;          // 782
  const int GW01 = MB64;                         // layers 0/1: 4 nb-tiles per block (N=256)
  const int GW2 = (MB64 + 3) / 4;                // layer 2: nblk=1, 4 mb-tiles per block

  // ---- dtype detection + constant prep + cursor zero ----
  k_detect_prep<<<1, 256, 0, stream>>>((const unsigned short*)in_feat, flag,
                                       al0, ar0, al1, ar1, al2, ar2, b0, b1, b2, att, cursor);

  // ---- CSR build ----
  k_hist<<<EB, 256, 0, stream>>>(dst, cursor);
  k_scan_blocks<<<SCAN_NB, SCAN_B, 0, stream>>>(cursor, rowptr, partial);
  k_scan_partials<<<1, 128, 0, stream>>>(partial, rowptr);
  k_scan_add<<<(N_NODES + 255) / 256, 256, 0, stream>>>(rowptr, partial, cursor);
  k_scatter<<<EB, 256, 0, stream>>>(src, dst, rowptr, cursor, csr_src);

  // ---- weight transposes (merged, -> bf16 [N][K]) ----
  k_transpose_all<<<(TW2 + 255) / 256, 256, 0, stream>>>(W0, W1, W2, w0t, w1t, w2t, flag);

  // ---- layer 0 (cast + el/er fused into GEMM) ----
  k_gemmw<<<GW01, 256, 0, stream>>>(in_feat, w0t, feat16, N_NODES, IN_F, HID, flag, 0,
                                    att + AT_AL0, att + AT_AR0, el, er, 1);
  k_aggregate8<<<N_NODES, 256, 0, stream>>>(rowptr, csr_src, (const uint4*)feat16, el, er, att + AT_B0, h16);

  // ---- layer 1 ----
  k_gemmw<<<GW01, 256, 0, stream>>>(h16, w1t, feat16, N_NODES, HID, HID, flag, 1,
                                    att + AT_AL1, att + AT_AR1, el, er, 1);
  k_aggregate8<<<N_NODES, 256, 0, stream>>>(rowptr, csr_src, (const uint4*)feat16, el, er, att + AT_B1, h16);

  // ---- layer 2 (feat16 reused as [N][64] padded feat2) ----
  k_gemmw<<<GW2, 256, 0, stream>>>(h16, w2t, feat16, N_NODES, HID, NCLS_PAD, flag, 1,
                                   nullptr, nullptr, nullptr, nullptr, 0);
  k_eler2<<<(N_NODES + 255) / 256, 256, 0, stream>>>(feat16, att + AT_AL2, att + AT_AR2, el, er);
  k_aggregate1<<<N_NODES, 256, 0, stream>>>(rowptr, csr_src, (const uint4*)feat16, el, er, att + AT_B2, d_out, flag);
}